// Round 12
// baseline (433.122 us; speedup 1.0000x reference)
//
#include <hip/hip_runtime.h>
#include <math.h>

#define N_TOK 32768
#define K_CODES 4096
#define DIM 512
#define COMMIT 0.25f
#define NCAND 8
#define NSPLIT 2
#define SPLIT_CODES (K_CODES / NSPLIT)   // 2048
#define NITER (SPLIT_CODES / 256)        // 8 col-iterations of 256 codes
#define BIAS 0.125f

typedef short s16x8 __attribute__((ext_vector_type(8)));
typedef float f32x4 __attribute__((ext_vector_type(4)));
typedef unsigned int uint32;
typedef unsigned long long u64;
typedef unsigned short u16;

__device__ __forceinline__ u16 f2bf(float f) {
    uint32 b = __float_as_uint(f);
    return (u16)((b + 0x7FFFu + ((b >> 16) & 1u)) >> 16);
}

// global -> LDS direct DMA, 16B per lane. LDS dest wave-uniform; HW writes
// lds + lane*16. Source address is per-lane (pre-swizzled).
__device__ __forceinline__ void gload16(const u16* g, u16* l) {
    __builtin_amdgcn_global_load_lds(
        (const __attribute__((address_space(1))) void*)g,
        (__attribute__((address_space(3))) void*)l,
        16, 0, 0);
}

// ---------------------------------------------------------------------------
// FUSED prep: fp32->bf16 (RNE) + numpy-exact pairwise row sum-of-squares.
// R11-verified, byte-identical.
// ---------------------------------------------------------------------------
__global__ __launch_bounds__(256) void prep_kernel(const float* __restrict__ src,
                                                   u16* __restrict__ bf,
                                                   float* __restrict__ sq) {
    #pragma clang fp contract(off)
    const int tid  = threadIdx.x;
    const int row0 = blockIdx.x * 32;

    {
        const float4* s4 = (const float4*)src + (size_t)row0 * 128;
        ushort4*      d4 = (ushort4*)bf + (size_t)row0 * 128;
        #pragma unroll
        for (int i = 0; i < 16; ++i) {
            int e = tid + i * 256;
            float4 v = s4[e];
            ushort4 o;
            o.x = f2bf(v.x); o.y = f2bf(v.y); o.z = f2bf(v.z); o.w = f2bf(v.w);
            d4[e] = o;
        }
    }

    const int lane = tid & 63;
    const int wvi  = tid >> 6;
    const int row  = row0 + wvi * 8 + (lane >> 3);
    const int j    = lane & 7;
    const float* p = src + (size_t)row * DIM;
    float blk[4];
    #pragma unroll
    for (int b = 0; b < 4; ++b) {
        const float* q = p + b * 128;
        float v = q[j];
        float r = v * v;
        for (int i = 8; i < 128; i += 8) { float u = q[i + j]; r += u * u; }
        float s1 = r  + __shfl_xor(r, 1);
        float s2 = s1 + __shfl_xor(s1, 2);
        float s3 = s2 + __shfl_xor(s2, 4);
        blk[b] = s3;
    }
    float res = (blk[0] + blk[1]) + (blk[2] + blk[3]);
    if (j == 0) sq[row] = res;
}

// ---------------------------------------------------------------------------
// MFMA bf16 screen — FAT TILE (R8 geometry, de-risked). 256 tok x 256 codes
// per column-iteration (NITER=8). 8 waves: wt=wv>>1 token quarter (64 rows),
// wcc=wv&1 code half (128 codes). Wave tile 64x128, acc[4][8]=128 VGPR.
// Key deltas vs R8 (which spilled 150 MB at cap 128):
//   - __launch_bounds__(512,1): compiler VGPR cap 256 (R10-proven).
//   - w2 table staged in LDS (kills per-it global loads + their registers).
//   - single-fragment inner loop (af[4]+bf one at a time).
// Double-buffered LDS: X 2x32K + W 2x32K + w2 8K = 136 KiB. R2-style drain
// schedule (prefetch chunk kc+1 during kc, __syncthreads drains). Staged
// bytes 1.05 GB/dispatch vs 1.57 (131 vs 87 FLOP/B) — attacks the measured
// ~12-22 B/cyc/CU DMA supply wall. Grid (128,2)=256 blocks = 1/CU exact.
// Screening semantics identical to R8-verified: top-2 per (wcc,n15) 64-code
// bucket, id=(it<<3)|c, 64 entries/token -> top-6/split, NCAND=8 refine.
// ---------------------------------------------------------------------------
__global__ __launch_bounds__(512, 1) void screen_kernel(const u16* __restrict__ xb,
                                                        const u16* __restrict__ wb,
                                                        const float* __restrict__ w2f,
                                                        u64* __restrict__ candPart) {
    __shared__ __attribute__((aligned(16))) u16 POOL[69632];  // 136 KiB
    // u16 units: X0 @0, X1 @16384, W0 @32768, W1 @49152 (each 256 rows x 64),
    //            w2 table @65536 (2048 floats = 8 KiB).
    // Merge phase reuses first 128 KiB as 256 tok x 64 u64.

    const int tid  = threadIdx.x;
    const int wv   = tid >> 6;
    const int wt   = wv >> 1;          // token quarter (0..3), 64 rows each
    const int wcc  = wv & 1;           // code half (0/1), 128 codes each
    const int lane = tid & 63;
    const int quad = lane >> 4;
    const int n15  = lane & 15;
    const int m0   = blockIdx.x * 256;
    const int sbase = blockIdx.y * SPLIT_CODES;

    // DMA geometry: 1 instr = 64 lanes x 16B = 8 rows x 8 quanta (128B rows).
    // phys quantum p at row r holds logical p^(r&7); r&7 == lane>>3 for
    // 8-aligned row bases -> src quantum = (lane&7)^(lane>>3).
    const int l8  = lane >> 3;
    const int qsw = (lane & 7) ^ l8;

    // X: 256 rows, 32 per wave -> 4 instrs (j*8 rows each).
    const u16* xg = xb + (size_t)(m0 + wv * 32 + l8) * DIM + qsw * 8;
    // W: 256 rows/chunk, 32 per wave -> 4 instrs; per-it base advances 256 rows.
    const u16* wit = wb + (size_t)(sbase + wv * 32 + l8) * DIM + qsw * 8;

    // prologue: w2 table into LDS (BIAS pre-added)
    {
        float* w2l = (float*)&POOL[65536];
        for (int i = tid; i < SPLIT_CODES; i += 512)
            w2l[i] = w2f[sbase + i] + BIAS;
    }

    uint32 r1[16], r2[16];
    #pragma unroll
    for (int i = 0; i < 16; ++i) { r1[i] = 0xFFFFFFFFu; r2[i] = 0xFFFFFFFFu; }

    // prologue: stage it=0 chunk 0 into buffer 0
    #pragma unroll
    for (int j = 0; j < 4; ++j) {
        gload16(xg + (size_t)(j * 8) * DIM, &POOL[wv * 2048 + j * 512]);
        gload16(wit + (size_t)(j * 8) * DIM, &POOL[32768 + wv * 2048 + j * 512]);
    }
    __syncthreads();

    for (int it = 0; it < NITER; ++it) {
        f32x4 acc[4][8];
        #pragma unroll
        for (int i = 0; i < 4; ++i)
            #pragma unroll
            for (int c = 0; c < 8; ++c) acc[i][c] = (f32x4){0.f, 0.f, 0.f, 0.f};

        for (int kc = 0; kc < 8; ++kc) {
            // prefetch chunk kc+1 of this column, or chunk 0 of next column
            if (kc < 7) {
                const int nb = (kc + 1) & 1;
                const int ko = (kc + 1) * 64;
                #pragma unroll
                for (int j = 0; j < 4; ++j) {
                    gload16(xg + (size_t)(j * 8) * DIM + ko,
                            &POOL[nb * 16384 + wv * 2048 + j * 512]);
                    gload16(wit + (size_t)(j * 8) * DIM + ko,
                            &POOL[32768 + nb * 16384 + wv * 2048 + j * 512]);
                }
            } else if (it < NITER - 1) {
                const u16* wn = wit + (size_t)256 * DIM;
                #pragma unroll
                for (int j = 0; j < 4; ++j) {
                    gload16(xg + (size_t)(j * 8) * DIM, &POOL[wv * 2048 + j * 512]);
                    gload16(wn + (size_t)(j * 8) * DIM, &POOL[32768 + wv * 2048 + j * 512]);
                }
            }

            const u16* X = &POOL[(kc & 1) * 16384];
            const u16* W = &POOL[32768 + (kc & 1) * 16384];
            #pragma unroll
            for (int s = 0; s < 2; ++s) {
                const int lq = s * 4 + quad;
                s16x8 af[4];
                #pragma unroll
                for (int i = 0; i < 4; ++i) {
                    const int tr = wt * 64 + i * 16 + n15;      // tr&7 == n15&7
                    af[i] = *(const s16x8*)&X[tr * 64 + (lq ^ (tr & 7)) * 8];
                }
                #pragma unroll
                for (int c = 0; c < 8; ++c) {
                    const int cr = wcc * 128 + c * 16 + n15;    // cr&7 == n15&7
                    s16x8 bf = *(const s16x8*)&W[cr * 64 + (lq ^ (cr & 7)) * 8];
                    #pragma unroll
                    for (int i = 0; i < 4; ++i)
                        acc[i][c] = __builtin_amdgcn_mfma_f32_16x16x32_bf16(af[i], bf, acc[i][c], 0, 0, 0);
                }
            }
            __syncthreads();   // drain -> staged chunk visible
        }

        // fold this 256-code column into running top-2 per (lane, token-slot)
        const float* w2l = (const float*)&POOL[65536];
        float w2pb[8];
        #pragma unroll
        for (int c = 0; c < 8; ++c)
            w2pb[c] = w2l[it * 256 + wcc * 128 + c * 16 + n15];
        #pragma unroll
        for (int i = 0; i < 4; ++i)
            #pragma unroll
            for (int r = 0; r < 4; ++r) {
                const int ti = i * 4 + r;
                #pragma unroll
                for (int c = 0; c < 8; ++c) {
                    float s = fmaf(-2.0f, acc[i][c][r], w2pb[c]);
                    uint32 key = (__float_as_uint(s) & 0xFFFFFFC0u) | (uint32)((it << 3) | c);
                    uint32 mx = r1[ti] > key ? r1[ti] : key;
                    r1[ti] = r1[ti] < key ? r1[ti] : key;
                    r2[ti] = r2[ti] < mx ? r2[ti] : mx;
                }
            }
        wit += (size_t)256 * DIM;
    }

    // ------- merge: 256 tokens x 64 entries via LDS (128 KiB), one phase ----
    // All waves passed the final kc-barrier; MS writes are disjoint slots;
    // one barrier before the reduction. (R8-verified structure.)
    u64* MS = (u64*)POOL;   // 256 tokens x 64 entries = 128 KiB
    #pragma unroll
    for (int ti = 0; ti < 16; ++ti) {
        const int i = ti >> 2, r = ti & 3;
        const int tloc = wt * 64 + i * 16 + quad * 4 + r;    // 0..255
        #pragma unroll
        for (int e = 0; e < 2; ++e) {
            uint32 k  = e ? r2[ti] : r1[ti];
            uint32 vb = k & 0xFFFFFFC0u;
            uint32 id = k & 63u;
            uint32 code = (uint32)(sbase + (id >> 3) * 256 + wcc * 128 + (id & 7) * 16 + n15);
            MS[tloc * 64 + (wcc * 16 + n15) * 2 + e] = ((u64)vb << 32) | code;
        }
    }
    __syncthreads();
    if (tid < 256) {
        u64 best[6];
        #pragma unroll
        for (int c = 0; c < 6; ++c) best[c] = 0xFFFFFFFFFFFFFFFFull;
        for (int e = 0; e < 64; ++e) {
            u64 v = MS[tid * 64 + e];
            if (v < best[5]) {
                best[5] = v;
                #pragma unroll
                for (int p = 5; p > 0; --p)
                    if (best[p] < best[p - 1]) { u64 tv = best[p]; best[p] = best[p - 1]; best[p - 1] = tv; }
            }
        }
        const int token = m0 + tid;
        u64* dst = candPart + ((size_t)blockIdx.y * N_TOK + token) * 6;
        #pragma unroll
        for (int c = 0; c < 6; ++c) dst[c] = best[c];
    }
}

// ---------------------------------------------------------------------------
// FUSED mergecand + np-exact refine + gather/loss/counts (R11-verified).
// ---------------------------------------------------------------------------
__global__ __launch_bounds__(256) void refine_gather_kernel(
        const float* __restrict__ x, const float* __restrict__ w,
        const float* __restrict__ x2np, const float* __restrict__ w2np,
        const u64* __restrict__ candPart,
        float* __restrict__ out_q, float* __restrict__ out_loss,
        float* __restrict__ out_ind, int* __restrict__ counts) {
    const int t    = blockIdx.x * 4 + (threadIdx.x >> 6);
    const int lane = threadIdx.x & 63;

    u64 best[NCAND];
    #pragma unroll
    for (int c = 0; c < NCAND; ++c) best[c] = 0xFFFFFFFFFFFFFFFFull;
    #pragma unroll
    for (int s = 0; s < NSPLIT; ++s) {
        const u64* src = candPart + ((size_t)s * N_TOK + t) * 6;
        #pragma unroll
        for (int c = 0; c < 6; ++c) {
            u64 v = src[c];
            if (v < best[NCAND - 1]) {
                best[NCAND - 1] = v;
                #pragma unroll
                for (int p = NCAND - 1; p > 0; --p)
                    if (best[p] < best[p - 1]) { u64 tv = best[p]; best[p] = best[p - 1]; best[p - 1] = tv; }
            }
        }
    }

    const float* xr = x + (size_t)t * DIM;
    float xv[8];
    #pragma unroll
    for (int j = 0; j < 8; ++j) xv[j] = xr[lane + 64 * j];
    const float x2 = x2np[t];

    float bd = 3.4e38f;
    int   bk = 0x7fffffff;
    for (int c = 0; c < NCAND; ++c) {
        int k = (int)(best[c] & 0xFFFu);
        const float* wr = w + (size_t)k * DIM;
        double m = 0.0;
        #pragma unroll
        for (int j = 0; j < 8; ++j)
            m = fma((double)xv[j], (double)wr[lane + 64 * j], m);
        #pragma unroll
        for (int off = 32; off >= 1; off >>= 1) m += __shfl_down(m, off);
        if (lane == 0) {
            #pragma clang fp contract(off)
            float m32 = (float)m;
            float T1  = x2 + w2np[k];
            float d   = T1 - 2.0f * m32;
            if (d < bd || (d == bd && k < bk)) { bd = d; bk = k; }
        }
    }
    const int kk = __shfl(bk, 0);   // lane0's winner

    const float4* xr4 = (const float4*)(x + (size_t)t * DIM);
    const float4* wr4 = (const float4*)(w + (size_t)kk * DIM);
    float4*       qo  = (float4*)(out_q + (size_t)t * DIM);

    float ss = 0.f;
    #pragma unroll
    for (int j = 0; j < 2; ++j) {
        int e = lane + j * 64;
        float4 xv4 = xr4[e];
        float4 wv4 = wr4[e];
        float4 d, o;
        d.x = wv4.x - xv4.x; o.x = xv4.x + d.x;
        d.y = wv4.y - xv4.y; o.y = xv4.y + d.y;
        d.z = wv4.z - xv4.z; o.z = xv4.z + d.z;
        d.w = wv4.w - xv4.w; o.w = xv4.w + d.w;
        ss += d.x * d.x + d.y * d.y + d.z * d.z + d.w * d.w;
        qo[e] = o;
    }
    #pragma unroll
    for (int off = 32; off >= 1; off >>= 1) ss += __shfl_down(ss, off);
    if (lane == 0) {
        float lm = ss * (1.0f / DIM);
        out_loss[t] = lm + COMMIT * lm;
        out_ind[t] = (float)kk;
        atomicAdd(&counts[kk], 1);
    }
}

// ---------------------------------------------------------------------------
// perplexity (R3-verified).
// ---------------------------------------------------------------------------
__global__ __launch_bounds__(256) void perplex_kernel(const int* __restrict__ counts,
                                                      float* __restrict__ out2) {
    __shared__ double red[4];
    const int tid = threadIdx.x;
    const int lane = tid & 63;
    const int wid = tid >> 6;
    double s = 0.0;
    for (int t = tid; t < K_CODES; t += 256) {
        int c = counts[t];
        if (c) {
            double p = (double)c * (1.0 / N_TOK);
            s += p * log(p + 1e-10);
        }
    }
    #pragma unroll
    for (int off = 32; off >= 1; off >>= 1) s += __shfl_down(s, off);
    if (lane == 0) red[wid] = s;
    __syncthreads();
    if (tid == 0) {
        double t = red[0] + red[1] + red[2] + red[3];
        out2[0] = (float)exp(-t);
    }
}

// ---------------------------------------------------------------------------
extern "C" void kernel_launch(void* const* d_in, const int* in_sizes, int n_in,
                              void* d_out, int out_size, void* d_ws, size_t ws_size,
                              hipStream_t stream) {
    const float* x = (const float*)d_in[0];
    const float* w = (const float*)d_in[1];

    float* out0 = (float*)d_out;                       // quantized_st [N,D]
    float* out1 = out0 + (size_t)N_TOK * DIM;          // loss [N]
    float* out2 = out1 + N_TOK;                        // perplexity [1]
    float* out3 = out2 + 1;                            // indices [N] (as float)

    // workspace layout (8B-aligned chunks first)
    u64*   candPart = (u64*)d_ws;                                 // NSPLIT*N_TOK*6
    float* x2np     = (float*)(candPart + (size_t)NSPLIT * N_TOK * 6);
    float* w2np     = x2np + N_TOK;
    int*   idx      = (int*)(w2np + K_CODES);
    int*   counts   = idx + N_TOK;
    int*   candF    = counts + K_CODES;                           // (unused now)
    u16*   x_bf     = (u16*)(candF + (size_t)N_TOK * NCAND);      // N_TOK*DIM
    u16*   w_bf     = x_bf + (size_t)N_TOK * DIM;                 // K_CODES*DIM

    hipMemsetAsync(counts, 0, K_CODES * sizeof(int), stream);

    prep_kernel<<<N_TOK / 32, 256, 0, stream>>>(x, x_bf, x2np);
    prep_kernel<<<K_CODES / 32, 256, 0, stream>>>(w, w_bf, w2np);
    screen_kernel<<<dim3(N_TOK / 256, NSPLIT), 512, 0, stream>>>(x_bf, w_bf, w2np, candPart);
    refine_gather_kernel<<<N_TOK / 4, 256, 0, stream>>>(x, w, x2np, w2np, candPart,
                                                        out0, out1, out3, counts);
    perplex_kernel<<<1, 256, 0, stream>>>(counts, out2);
}